// Round 7
// baseline (539.227 us; speedup 1.0000x reference)
//
#include <hip/hip_runtime.h>
#include <cstdint>

#define F_IN  128
#define F_HID 16
#define F_HALF 8
#define F_OUT 138
#define NBUCK 256        // dst buckets
#define NPB_SHIFT 9
#define NPB 512          // nodes per bucket
#define NB  256          // edge slabs (= blocks) for binning passes

// ---------------------------------------------------------------------------
// Inline edge_index dtype detection: int64 (LE, values < 2^31) -> every odd
// int32 word is zero. Returns 2 (int64 stride in words) or 1 (int32).
__device__ __forceinline__ int edge_mult(const int* __restrict__ idx) {
    int nz = 0;
#pragma unroll
    for (int i = 1; i < 64; i += 2) nz |= idx[i];
    return nz ? 1 : 2;
}

// Pass A: per-block LDS histogram of dst-buckets over this block's edge slab.
__global__ void k_bincount(const int* __restrict__ idx,
                           unsigned* __restrict__ cnt, int E) {
    __shared__ unsigned hist[NBUCK];
    int tid = threadIdx.x;
    for (int i = tid; i < NBUCK; i += 256) hist[i] = 0;
    __syncthreads();
    const int mult = edge_mult(idx);
    int slab = (E + NB - 1) / NB;
    int start = blockIdx.x * slab, end = min(E, start + slab);
    if (mult == 2) {
        for (int e = start + tid; e < end; e += 256) {
            int d = ((const int2*)idx)[(size_t)E + e].x;
            atomicAdd(&hist[d >> NPB_SHIFT], 1u);
        }
    } else {
        for (int e = start + tid; e < end; e += 256) {
            int d = idx[(size_t)E + e];
            atomicAdd(&hist[d >> NPB_SHIFT], 1u);
        }
    }
    __syncthreads();
    for (int i = tid; i < NBUCK; i += 256) cnt[(size_t)i * NB + blockIdx.x] = hist[i];
}

// Scan cnt[bucket][block] -> exclusive offsets; emits bucketPtr[].
__global__ void k_scan(unsigned* __restrict__ cnt, unsigned* __restrict__ bucketPtr, int E) {
    __shared__ unsigned tot[NBUCK];
    int t = threadIdx.x;
    unsigned run = 0;
    for (int b = 0; b < NB; ++b) {
        unsigned c = cnt[(size_t)t * NB + b];
        cnt[(size_t)t * NB + b] = run;
        run += c;
    }
    tot[t] = run;
    __syncthreads();
    if (t == 0) {
        unsigned r = 0;
        for (int i = 0; i < NBUCK; ++i) { unsigned c = tot[i]; tot[i] = r; bucketPtr[i] = r; r += c; }
        bucketPtr[NBUCK] = r;   // == E
    }
    __syncthreads();
    unsigned base = tot[t];
    for (int b = 0; b < NB; ++b) cnt[(size_t)t * NB + b] += base;
}

// Pass B: re-read slab, place each edge in its (block,bucket) segment via LDS
// cursors. Packed entry: (dstLocal<<17) | src  (9+17 = 26 bits, src < 2^17).
__global__ void k_binfill(const int* __restrict__ idx,
                          const unsigned* __restrict__ cnt,
                          unsigned* __restrict__ binned, int E) {
    __shared__ unsigned cur[NBUCK];
    int tid = threadIdx.x;
    for (int i = tid; i < NBUCK; i += 256) cur[i] = cnt[(size_t)i * NB + blockIdx.x];
    __syncthreads();
    const int mult = edge_mult(idx);
    int slab = (E + NB - 1) / NB;
    int start = blockIdx.x * slab, end = min(E, start + slab);
    for (int e = start + tid; e < end; e += 256) {
        int s, d;
        if (mult == 2) { s = ((const int2*)idx)[e].x; d = ((const int2*)idx)[(size_t)E + e].x; }
        else           { s = idx[e];                  d = idx[(size_t)E + e]; }
        unsigned pos = atomicAdd(&cur[d >> NPB_SHIFT], 1u);
        binned[pos] = ((unsigned)(d & (NPB - 1)) << 17) | (unsigned)s;
    }
}

// Fused per-bucket: degree histogram -> LDS exclusive scan -> ptr[], dinv[],
// then scatter binned -> col[] in CSR order via the same LDS bases. Writes
// land in the bucket's own ~130 KB col window -> L2-resident.
__global__ void k_ptrfill(const unsigned* __restrict__ bucketPtr,
                          const unsigned* __restrict__ binned,
                          unsigned* __restrict__ ptr, float* __restrict__ dinv,
                          int* __restrict__ col, int n, int E) {
    __shared__ unsigned deg[NPB];
    __shared__ unsigned sh[256];
    __shared__ unsigned cur[NPB];
    int tid = threadIdx.x, bb = blockIdx.x;
    for (int i = tid; i < NPB; i += 256) deg[i] = 0;
    __syncthreads();
    unsigned start = bucketPtr[bb], end = bucketPtr[bb + 1];
    for (unsigned i = start + tid; i < end; i += 256)
        atomicAdd(&deg[binned[i] >> 17], 1u);
    __syncthreads();
    unsigned d0 = deg[2 * tid], d1 = deg[2 * tid + 1];
    unsigned pair = d0 + d1;
    sh[tid] = pair;
    __syncthreads();
    for (int off = 1; off < 256; off <<= 1) {
        unsigned v = (tid >= off) ? sh[tid - off] : 0u;
        __syncthreads();
        sh[tid] += v;
        __syncthreads();
    }
    unsigned excl = sh[tid] - pair;
    unsigned base0 = start + excl, base1 = base0 + d0;
    cur[2 * tid] = base0;
    cur[2 * tid + 1] = base1;
    int v0 = (bb << NPB_SHIFT) + 2 * tid;
    if (v0 < n)     { ptr[v0] = base0;     dinv[v0] = rsqrtf((float)(d0 + 1u)); }
    if (v0 + 1 < n) { ptr[v0 + 1] = base1; dinv[v0 + 1] = rsqrtf((float)(d1 + 1u)); }
    if (bb == 0 && tid == 0) ptr[n] = (unsigned)E;
    __syncthreads();
    for (unsigned i = start + tid; i < end; i += 256) {
        unsigned entry = binned[i];
        unsigned pos = atomicAdd(&cur[entry >> 17], 1u);
        col[pos] = (int)(entry & 0x1FFFFu);
    }
}

// g1[v][j] = dinv[v] * (x[v] . W1[:,j]); written HALF-SPLIT: j<8 -> gA[v][j],
// j>=8 -> gB[v][j-8]. Each half table is 3.2 MB -> fits a 4 MB XCD L2.
__global__ void k_gemm1(const float* __restrict__ x, const float* __restrict__ W1,
                        const float* __restrict__ dinv,
                        float* __restrict__ gA, float* __restrict__ gB, int n) {
    __shared__ float w1s[F_IN * F_HID];     // 8 KB
    __shared__ float xs[16][F_IN + 4];
    int tid = threadIdx.x;
    for (int i = tid; i < F_IN * F_HID; i += 256) w1s[i] = W1[i];
    int nb = blockIdx.x * 16;
    for (int q = tid; q < 512; q += 256) {
        int r = q >> 5, k4 = q & 31;
        int g = nb + r;
        float4 v = make_float4(0.f, 0.f, 0.f, 0.f);
        if (g < n) v = ((const float4*)x)[(size_t)g * 32 + k4];
        xs[r][k4 * 4 + 0] = v.x; xs[r][k4 * 4 + 1] = v.y;
        xs[r][k4 * 4 + 2] = v.z; xs[r][k4 * 4 + 3] = v.w;
    }
    __syncthreads();
    int r = tid >> 4, j = tid & 15;
    int g = nb + r;
    if (g < n) {
        float acc = 0.f;
#pragma unroll
        for (int k = 0; k < F_IN; ++k) acc += xs[r][k] * w1s[k * F_HID + j];
        float v = acc * dinv[g];
        if (j < F_HALF) gA[(size_t)g * F_HALF + j] = v;
        else            gB[(size_t)g * F_HALF + (j - F_HALF)] = v;
    }
}

// Pull-mode CSR aggregation over ONE feature half (8 lanes per node).
// gin is a 3.2 MB table -> L2-resident per XCD; col is streamed with
// non-temporal loads so it doesn't evict the table. 8-way unrolled
// independent gathers; no LDS, no atomics. Self-loop = accumulator init.
// Epilogue: RELU=1: gout = relu(dinv*acc + b1h[j]) * dinv; RELU=0: dinv*acc.
template <int RELU>
__global__ void __launch_bounds__(256)
k_agg(const unsigned* __restrict__ ptr, const int* __restrict__ col,
      const float* __restrict__ gin, float* __restrict__ gout,
      const float* __restrict__ dinv, const float* __restrict__ b1h, int n) {
    int t = blockIdx.x * blockDim.x + threadIdx.x;
    int v = t >> 3, j = t & 7;
    if (v >= n) return;
    float acc = gin[(size_t)v * F_HALF + j];   // self-loop
    unsigned i = ptr[v], end = ptr[v + 1];
    for (; i + 8 <= end; i += 8) {
        int u0 = __builtin_nontemporal_load(col + i);
        int u1 = __builtin_nontemporal_load(col + i + 1);
        int u2 = __builtin_nontemporal_load(col + i + 2);
        int u3 = __builtin_nontemporal_load(col + i + 3);
        int u4 = __builtin_nontemporal_load(col + i + 4);
        int u5 = __builtin_nontemporal_load(col + i + 5);
        int u6 = __builtin_nontemporal_load(col + i + 6);
        int u7 = __builtin_nontemporal_load(col + i + 7);
        float a0 = gin[(size_t)u0 * F_HALF + j];
        float a1 = gin[(size_t)u1 * F_HALF + j];
        float a2 = gin[(size_t)u2 * F_HALF + j];
        float a3 = gin[(size_t)u3 * F_HALF + j];
        float a4 = gin[(size_t)u4 * F_HALF + j];
        float a5 = gin[(size_t)u5 * F_HALF + j];
        float a6 = gin[(size_t)u6 * F_HALF + j];
        float a7 = gin[(size_t)u7 * F_HALF + j];
        acc += ((a0 + a1) + (a2 + a3)) + ((a4 + a5) + (a6 + a7));
    }
    for (; i < end; ++i)
        acc += gin[(size_t)__builtin_nontemporal_load(col + i) * F_HALF + j];
    float di = dinv[v];
    float r;
    if (RELU) r = fmaxf(di * acc + b1h[j], 0.f) * di;
    else      r = di * acc;
    __builtin_nontemporal_store(r, gout + (size_t)v * F_HALF + j);
}

// out[v][c] = [BA[v],BB[v]] . W2[:,c] + b2[c]   (dinv already folded in)
__global__ void k_out(const float* __restrict__ BA, const float* __restrict__ BB,
                      const float* __restrict__ W2, const float* __restrict__ b2,
                      float* __restrict__ out, int n) {
    __shared__ float w2s[F_HID * F_OUT];
    __shared__ float b2s[F_OUT];
    int tid = threadIdx.x;
    for (int i = tid; i < F_HID * F_OUT; i += 256) w2s[i] = W2[i];
    if (tid < F_OUT) b2s[tid] = b2[tid];
    __syncthreads();
    int total = n * F_OUT;
    int stride = gridDim.x * blockDim.x;
    for (int i = blockIdx.x * blockDim.x + tid; i < total; i += stride) {
        int node = i / F_OUT, c = i - node * F_OUT;
        float acc = 0.f;
#pragma unroll
        for (int j = 0; j < F_HALF; ++j)
            acc += BA[(size_t)node * F_HALF + j] * w2s[j * F_OUT + c];
#pragma unroll
        for (int j = 0; j < F_HALF; ++j)
            acc += BB[(size_t)node * F_HALF + j] * w2s[(j + F_HALF) * F_OUT + c];
        out[i] = acc + b2s[c];
    }
}

extern "C" void kernel_launch(void* const* d_in, const int* in_sizes, int n_in,
                              void* d_out, int out_size, void* d_ws, size_t ws_size,
                              hipStream_t stream) {
    const float* x   = (const float*)d_in[0];
    const int*   idx = (const int*)d_in[1];
    const float* W1  = (const float*)d_in[2];
    const float* b1  = (const float*)d_in[3];
    const float* W2  = (const float*)d_in[4];
    const float* b2  = (const float*)d_in[5];
    float* out = (float*)d_out;

    const int n = in_sizes[0] / F_IN;       // 100000
    const int E = in_sizes[1] / 2;          // 6400000

    char* ws = (char*)d_ws;
    size_t off = 0;
    auto carve = [&](size_t bytes) { char* p = ws + off; off += (bytes + 255) / 256 * 256; return p; };
    float*    dinv      = (float*)carve((size_t)n * 4);
    unsigned* bucketPtr = (unsigned*)carve((NBUCK + 1) * 4);
    unsigned* cnt       = (unsigned*)carve((size_t)NBUCK * NB * 4);     // 256 KB
    unsigned* ptr       = (unsigned*)carve(((size_t)n + 1) * 4);
    float*    A0        = (float*)carve((size_t)n * F_HALF * 4);        // 3.2 MB half tables
    float*    A1        = (float*)carve((size_t)n * F_HALF * 4);
    float*    B0        = (float*)carve((size_t)n * F_HALF * 4);
    float*    B1        = (float*)carve((size_t)n * F_HALF * 4);
    // binned (E words = 25.6 MB) and col (E words) live in d_out (55.2 MB);
    // both fully consumed before k_out overwrites d_out.
    unsigned* binned = (unsigned*)d_out;
    int*      col    = (int*)d_out + (size_t)E;

    const int B = 256;
    const int nbAggH = (n * F_HALF + B - 1) / B;   // 3125
    k_bincount<<<NB, B, 0, stream>>>(idx, cnt, E);
    k_scan    <<<1, NBUCK, 0, stream>>>(cnt, bucketPtr, E);
    k_binfill <<<NB, B, 0, stream>>>(idx, cnt, binned, E);
    k_ptrfill <<<NBUCK, B, 0, stream>>>(bucketPtr, binned, ptr, dinv, col, n, E);
    k_gemm1   <<<(n + 15) / 16, B, 0, stream>>>(x, W1, dinv, A0, A1, n);
    // layer-1 aggregation, per feature-half (table L2-resident per pass)
    k_agg<1>  <<<nbAggH, B, 0, stream>>>(ptr, col, A0, B0, dinv, b1, n);
    k_agg<1>  <<<nbAggH, B, 0, stream>>>(ptr, col, A1, B1, dinv, b1 + F_HALF, n);
    // layer-2 aggregation (reuse A0/A1 as outputs)
    k_agg<0>  <<<nbAggH, B, 0, stream>>>(ptr, col, B0, A0, dinv, b1, n);
    k_agg<0>  <<<nbAggH, B, 0, stream>>>(ptr, col, B1, A1, dinv, b1, n);
    k_out     <<<8192, B, 0, stream>>>(A0, A1, W2, b2, out, n);
}

// Round 8
// 450.538 us; speedup vs baseline: 1.1969x; 1.1969x over previous
//
#include <hip/hip_runtime.h>
#include <cstdint>

#define F_IN  128
#define F_HID 16
#define F_OUT 138
#define NBUCK 256        // dst buckets
#define NPB_SHIFT 9
#define NPB 512          // nodes per bucket
#define NB  512          // edge slabs for binning passes

// ---------------------------------------------------------------------------
// Inline edge_index dtype detection: int64 (LE, values < 2^31) -> every odd
// int32 word is zero. Returns 2 (int64 stride in words) or 1 (int32).
__device__ __forceinline__ int edge_mult(const int* __restrict__ idx) {
    int nz = 0;
#pragma unroll
    for (int i = 1; i < 64; i += 2) nz |= idx[i];
    return nz ? 1 : 2;
}

// Pass A: per-slab LDS histogram of dst-buckets.
__global__ void k_bincount(const int* __restrict__ idx,
                           unsigned* __restrict__ cnt, int E) {
    __shared__ unsigned hist[NBUCK];
    int tid = threadIdx.x;
    for (int i = tid; i < NBUCK; i += 256) hist[i] = 0;
    __syncthreads();
    const int mult = edge_mult(idx);
    int slab = (E + NB - 1) / NB;
    int start = blockIdx.x * slab, end = min(E, start + slab);
    if (mult == 2) {
        for (int e = start + tid; e < end; e += 256) {
            int d = ((const int2*)idx)[(size_t)E + e].x;
            atomicAdd(&hist[d >> NPB_SHIFT], 1u);
        }
    } else {
        for (int e = start + tid; e < end; e += 256) {
            int d = idx[(size_t)E + e];
            atomicAdd(&hist[d >> NPB_SHIFT], 1u);
        }
    }
    __syncthreads();
    for (int i = tid; i < NBUCK; i += 256) cnt[(size_t)i * NB + blockIdx.x] = hist[i];
}

// Scan cnt[bucket][slab] -> exclusive offsets; emits bucketPtr[].
__global__ void k_scan(unsigned* __restrict__ cnt, unsigned* __restrict__ bucketPtr, int E) {
    __shared__ unsigned tot[NBUCK];
    int t = threadIdx.x;
    unsigned run = 0;
    for (int b = 0; b < NB; ++b) {
        unsigned c = cnt[(size_t)t * NB + b];
        cnt[(size_t)t * NB + b] = run;
        run += c;
    }
    tot[t] = run;
    __syncthreads();
    if (t == 0) {
        unsigned r = 0;
        for (int i = 0; i < NBUCK; ++i) { unsigned c = tot[i]; tot[i] = r; bucketPtr[i] = r; r += c; }
        bucketPtr[NBUCK] = r;   // == E
    }
    __syncthreads();
    unsigned base = tot[t];
    for (int b = 0; b < NB; ++b) cnt[(size_t)t * NB + b] += base;
}

// Pass B: re-read slab, place each edge in its (slab,bucket) segment via LDS
// cursors. Packed entry: (dstLocal<<17) | src  (9+17 = 26 bits, src < 2^17).
__global__ void k_binfill(const int* __restrict__ idx,
                          const unsigned* __restrict__ cnt,
                          unsigned* __restrict__ binned, int E) {
    __shared__ unsigned cur[NBUCK];
    int tid = threadIdx.x;
    for (int i = tid; i < NBUCK; i += 256) cur[i] = cnt[(size_t)i * NB + blockIdx.x];
    __syncthreads();
    const int mult = edge_mult(idx);
    int slab = (E + NB - 1) / NB;
    int start = blockIdx.x * slab, end = min(E, start + slab);
    for (int e = start + tid; e < end; e += 256) {
        int s, d;
        if (mult == 2) { s = ((const int2*)idx)[e].x; d = ((const int2*)idx)[(size_t)E + e].x; }
        else           { s = idx[e];                  d = idx[(size_t)E + e]; }
        unsigned pos = atomicAdd(&cur[d >> NPB_SHIFT], 1u);
        binned[pos] = ((unsigned)(d & (NPB - 1)) << 17) | (unsigned)s;
    }
}

// Fused per-bucket (1024 threads): slice-aware degree histogram -> LDS scan
// -> p0/p1 slice boundaries + dinv, then scatter binned -> col[] so each
// node's row is [slice0 srcs | slice1 srcs]. Writes land in the bucket's own
// col window -> L2-resident.
__global__ void __launch_bounds__(1024)
k_ptrfill(const unsigned* __restrict__ bucketPtr,
          const unsigned* __restrict__ binned,
          unsigned* __restrict__ p0, unsigned* __restrict__ p1,
          float* __restrict__ dinv, int* __restrict__ col,
          int n, int E, int s1) {
    __shared__ unsigned deg[NPB][2];   // 4 KB
    __shared__ unsigned cur[NPB][2];   // 4 KB
    __shared__ unsigned sh[NPB];       // 2 KB
    int tid = threadIdx.x, bb = blockIdx.x;
    for (int i = tid; i < NPB * 2; i += 1024) ((unsigned*)deg)[i] = 0;
    __syncthreads();
    unsigned start = bucketPtr[bb], end = bucketPtr[bb + 1];
    for (unsigned i = start + tid; i < end; i += 1024) {
        unsigned entry = binned[i];
        int dl = (int)(entry >> 17);
        int src = (int)(entry & 0x1FFFFu);
        atomicAdd(&deg[dl][src >= s1 ? 1 : 0], 1u);
    }
    __syncthreads();
    unsigned tot = 0, d0 = 0, d1 = 0;
    if (tid < NPB) { d0 = deg[tid][0]; d1 = deg[tid][1]; tot = d0 + d1; sh[tid] = tot; }
    __syncthreads();
    for (int off = 1; off < NPB; off <<= 1) {
        unsigned v = 0;
        if (tid < NPB && tid >= off) v = sh[tid - off];
        __syncthreads();
        if (tid < NPB) sh[tid] += v;
        __syncthreads();
    }
    if (tid < NPB) {
        unsigned base = start + sh[tid] - tot;   // exclusive prefix
        cur[tid][0] = base;
        cur[tid][1] = base + d0;
        int v = (bb << NPB_SHIFT) + tid;
        if (v < n) {
            p0[v] = base;
            p1[v] = base + d0;
            dinv[v] = rsqrtf((float)(tot + 1u));   // +1 self-loop
        }
    }
    if (bb == 0 && tid == 0) p0[n] = (unsigned)E;
    __syncthreads();
    for (unsigned i = start + tid; i < end; i += 1024) {
        unsigned entry = binned[i];
        int dl = (int)(entry >> 17);
        int src = (int)(entry & 0x1FFFFu);
        unsigned pos = atomicAdd(&cur[dl][src >= s1 ? 1 : 0], 1u);
        col[pos] = src;
    }
}

// g1[v][j] = dinv[v] * (x[v] . W1[:,j]).  16 nodes x 16 feats per block.
__global__ void k_gemm1(const float* __restrict__ x, const float* __restrict__ W1,
                        const float* __restrict__ dinv,
                        float* __restrict__ g1, int n) {
    __shared__ float w1s[F_IN * F_HID];     // 8 KB
    __shared__ float xs[16][F_IN + 4];
    int tid = threadIdx.x;
    for (int i = tid; i < F_IN * F_HID; i += 256) w1s[i] = W1[i];
    int nb = blockIdx.x * 16;
    for (int q = tid; q < 512; q += 256) {
        int r = q >> 5, k4 = q & 31;
        int g = nb + r;
        float4 v = make_float4(0.f, 0.f, 0.f, 0.f);
        if (g < n) v = ((const float4*)x)[(size_t)g * 32 + k4];
        xs[r][k4 * 4 + 0] = v.x; xs[r][k4 * 4 + 1] = v.y;
        xs[r][k4 * 4 + 2] = v.z; xs[r][k4 * 4 + 3] = v.w;
    }
    __syncthreads();
    int r = tid >> 4, j = tid & 15;
    int g = nb + r;
    if (g < n) {
        float acc = 0.f;
#pragma unroll
        for (int k = 0; k < F_IN; ++k) acc += xs[r][k] * w1s[k * F_HID + j];
        g1[(size_t)g * F_HID + j] = acc * dinv[g];
    }
}

// Pull-mode CSR aggregation over ONE src slice (full 16-wide rows, 16 lanes
// per node). Per pass all gathers hit a <=3.2 MB window of gin -> XCD-L2
// resident; col streamed NT; partial accumulator streamed NT.
// FIRST: acc = gin[v] (self-loop); else load partial from acc_io.
// LAST: epilogue (dinv, +b1/relu for layer 1) and store in place.
template <int FIRST, int LAST, int RELU>
__global__ void __launch_bounds__(256)
k_agg(const unsigned* __restrict__ pA, const unsigned* __restrict__ pB,
      const int* __restrict__ col,
      const float* __restrict__ gin, float* __restrict__ acc_io,
      const float* __restrict__ dinv, const float* __restrict__ b1, int n) {
    int t = blockIdx.x * blockDim.x + threadIdx.x;
    int v = t >> 4, j = t & 15;
    if (v >= n) return;
    size_t o = (size_t)v * F_HID + j;
    float acc;
    if (FIRST) acc = gin[o];                               // self-loop
    else       acc = __builtin_nontemporal_load(acc_io + o);
    unsigned i = pA[v], end = pB[v];
    for (; i + 8 <= end; i += 8) {
        int u0 = __builtin_nontemporal_load(col + i);
        int u1 = __builtin_nontemporal_load(col + i + 1);
        int u2 = __builtin_nontemporal_load(col + i + 2);
        int u3 = __builtin_nontemporal_load(col + i + 3);
        int u4 = __builtin_nontemporal_load(col + i + 4);
        int u5 = __builtin_nontemporal_load(col + i + 5);
        int u6 = __builtin_nontemporal_load(col + i + 6);
        int u7 = __builtin_nontemporal_load(col + i + 7);
        float a0 = gin[(size_t)u0 * F_HID + j];
        float a1 = gin[(size_t)u1 * F_HID + j];
        float a2 = gin[(size_t)u2 * F_HID + j];
        float a3 = gin[(size_t)u3 * F_HID + j];
        float a4 = gin[(size_t)u4 * F_HID + j];
        float a5 = gin[(size_t)u5 * F_HID + j];
        float a6 = gin[(size_t)u6 * F_HID + j];
        float a7 = gin[(size_t)u7 * F_HID + j];
        acc += ((a0 + a1) + (a2 + a3)) + ((a4 + a5) + (a6 + a7));
    }
    for (; i < end; ++i)
        acc += gin[(size_t)__builtin_nontemporal_load(col + i) * F_HID + j];
    if (LAST) {
        float di = dinv[v];
        float r;
        if (RELU) r = fmaxf(di * acc + b1[j], 0.f) * di;
        else      r = di * acc;
        __builtin_nontemporal_store(r, acc_io + o);
    } else {
        __builtin_nontemporal_store(acc, acc_io + o);
    }
}

// out[v][c] = B[v] . W2[:,c] + b2[c]   (dinv already folded into B)
__global__ void k_out(const float* __restrict__ B,
                      const float* __restrict__ W2, const float* __restrict__ b2,
                      float* __restrict__ out, int n) {
    __shared__ float w2s[F_HID * F_OUT];
    __shared__ float b2s[F_OUT];
    int tid = threadIdx.x;
    for (int i = tid; i < F_HID * F_OUT; i += 256) w2s[i] = W2[i];
    if (tid < F_OUT) b2s[tid] = b2[tid];
    __syncthreads();
    int total = n * F_OUT;
    int stride = gridDim.x * blockDim.x;
    for (int i = blockIdx.x * blockDim.x + tid; i < total; i += stride) {
        int node = i / F_OUT, c = i - node * F_OUT;
        float acc = 0.f;
#pragma unroll
        for (int j = 0; j < F_HID; ++j) acc += B[(size_t)node * F_HID + j] * w2s[j * F_OUT + c];
        __builtin_nontemporal_store(acc + b2s[c], out + i);
    }
}

extern "C" void kernel_launch(void* const* d_in, const int* in_sizes, int n_in,
                              void* d_out, int out_size, void* d_ws, size_t ws_size,
                              hipStream_t stream) {
    const float* x   = (const float*)d_in[0];
    const int*   idx = (const int*)d_in[1];
    const float* W1  = (const float*)d_in[2];
    const float* b1  = (const float*)d_in[3];
    const float* W2  = (const float*)d_in[4];
    const float* b2  = (const float*)d_in[5];
    float* out = (float*)d_out;

    const int n = in_sizes[0] / F_IN;       // 100000
    const int E = in_sizes[1] / 2;          // 6400000
    const int s1 = (n + 1) / 2;             // src-slice boundary (3.2 MB halves)

    char* ws = (char*)d_ws;
    size_t off = 0;
    auto carve = [&](size_t bytes) { char* p = ws + off; off += (bytes + 255) / 256 * 256; return p; };
    float*    dinv      = (float*)carve((size_t)n * 4);
    unsigned* bucketPtr = (unsigned*)carve((NBUCK + 1) * 4);
    unsigned* cnt       = (unsigned*)carve((size_t)NBUCK * NB * 4);   // 512 KB
    unsigned* p0        = (unsigned*)carve(((size_t)n + 1) * 4);
    unsigned* p1        = (unsigned*)carve((size_t)n * 4);
    float*    bufA      = (float*)carve((size_t)n * F_HID * 4);       // 6.4 MB
    float*    bufB      = (float*)carve((size_t)n * F_HID * 4);       // 6.4 MB
    // binned (E words = 25.6 MB) and col (E words) live in d_out (55.2 MB);
    // both fully consumed before k_out overwrites d_out.
    unsigned* binned = (unsigned*)d_out;
    int*      col    = (int*)d_out + (size_t)E;

    const int B = 256;
    const int nbAgg = (n * F_HID + B - 1) / B;   // 6250
    k_bincount<<<NB, B, 0, stream>>>(idx, cnt, E);
    k_scan    <<<1, NBUCK, 0, stream>>>(cnt, bucketPtr, E);
    k_binfill <<<NB, B, 0, stream>>>(idx, cnt, binned, E);
    k_ptrfill <<<NBUCK, 1024, 0, stream>>>(bucketPtr, binned, p0, p1, dinv, col, n, E, s1);
    k_gemm1   <<<(n + 15) / 16, B, 0, stream>>>(x, W1, dinv, bufA, n);
    // layer 1: slice-0 pass (partial), slice-1 pass (+relu epilogue)
    k_agg<1,0,0><<<nbAgg, B, 0, stream>>>(p0, p1,     col, bufA, bufB, dinv, b1, n);
    k_agg<0,1,1><<<nbAgg, B, 0, stream>>>(p1, p0 + 1, col, bufA, bufB, dinv, b1, n);
    // layer 2
    k_agg<1,0,0><<<nbAgg, B, 0, stream>>>(p0, p1,     col, bufB, bufA, dinv, b1, n);
    k_agg<0,1,0><<<nbAgg, B, 0, stream>>>(p1, p0 + 1, col, bufB, bufA, dinv, b1, n);
    k_out     <<<8192, B, 0, stream>>>(bufA, W2, b2, out, n);
}

// Round 9
// 378.842 us; speedup vs baseline: 1.4234x; 1.1893x over previous
//
#include <hip/hip_runtime.h>
#include <cstdint>

#define F_IN  128
#define F_HID 16
#define F_OUT 138
#define NBUCK 256        // dst buckets
#define NPB_SHIFT 9
#define NPB 512          // nodes per bucket
#define NB  512          // edge slabs for binning passes

// ---------------------------------------------------------------------------
// Inline edge_index dtype detection: int64 (LE, values < 2^31) -> every odd
// int32 word is zero. Returns 2 (int64 stride in words) or 1 (int32).
__device__ __forceinline__ int edge_mult(const int* __restrict__ idx) {
    int nz = 0;
#pragma unroll
    for (int i = 1; i < 64; i += 2) nz |= idx[i];
    return nz ? 1 : 2;
}

// Pass A: per-slab LDS histogram of dst-buckets.
__global__ void k_bincount(const int* __restrict__ idx,
                           unsigned* __restrict__ cnt, int E) {
    __shared__ unsigned hist[NBUCK];
    int tid = threadIdx.x;
    for (int i = tid; i < NBUCK; i += 256) hist[i] = 0;
    __syncthreads();
    const int mult = edge_mult(idx);
    int slab = (E + NB - 1) / NB;
    int start = blockIdx.x * slab, end = min(E, start + slab);
    if (mult == 2) {
        for (int e = start + tid; e < end; e += 256) {
            int d = ((const int2*)idx)[(size_t)E + e].x;
            atomicAdd(&hist[d >> NPB_SHIFT], 1u);
        }
    } else {
        for (int e = start + tid; e < end; e += 256) {
            int d = idx[(size_t)E + e];
            atomicAdd(&hist[d >> NPB_SHIFT], 1u);
        }
    }
    __syncthreads();
    for (int i = tid; i < NBUCK; i += 256) cnt[(size_t)i * NB + blockIdx.x] = hist[i];
}

// Scan step 1: one block per bucket. Exclusive-scan the bucket's contiguous
// row of NB slab counts in place (pair-per-thread Hillis-Steele); emit total.
__global__ void k_scanA(unsigned* __restrict__ cnt, unsigned* __restrict__ bucketTot) {
    __shared__ unsigned sh[256];
    int t = threadIdx.x;
    unsigned* row = cnt + (size_t)blockIdx.x * NB;
    unsigned e0 = row[2 * t], e1 = row[2 * t + 1];
    unsigned pair = e0 + e1;
    sh[t] = pair;
    __syncthreads();
    for (int off = 1; off < 256; off <<= 1) {
        unsigned v = (t >= off) ? sh[t - off] : 0u;
        __syncthreads();
        sh[t] += v;
        __syncthreads();
    }
    unsigned excl = sh[t] - pair;      // exclusive prefix of this pair
    row[2 * t] = excl;
    row[2 * t + 1] = excl + e0;
    if (t == 255) bucketTot[blockIdx.x] = sh[255];
}

// Scan step 2: one block; exclusive scan of 256 bucket totals -> bucketPtr.
__global__ void k_scanB(const unsigned* __restrict__ bucketTot,
                        unsigned* __restrict__ bucketPtr) {
    __shared__ unsigned sh[NBUCK];
    int t = threadIdx.x;
    unsigned c = bucketTot[t];
    sh[t] = c;
    __syncthreads();
    for (int off = 1; off < NBUCK; off <<= 1) {
        unsigned v = (t >= off) ? sh[t - off] : 0u;
        __syncthreads();
        sh[t] += v;
        __syncthreads();
    }
    bucketPtr[t] = sh[t] - c;          // exclusive
    if (t == NBUCK - 1) bucketPtr[NBUCK] = sh[t];
}

// Pass B: re-read slab, place each edge in its (slab,bucket) segment via LDS
// cursors (within-bucket offset + bucket base added at load).
// Packed entry: (dstLocal<<17) | src  (9+17 = 26 bits, src < 2^17).
__global__ void k_binfill(const int* __restrict__ idx,
                          const unsigned* __restrict__ cnt,
                          const unsigned* __restrict__ bucketPtr,
                          unsigned* __restrict__ binned, int E) {
    __shared__ unsigned cur[NBUCK];
    int tid = threadIdx.x;
    for (int i = tid; i < NBUCK; i += 256)
        cur[i] = cnt[(size_t)i * NB + blockIdx.x] + bucketPtr[i];
    __syncthreads();
    const int mult = edge_mult(idx);
    int slab = (E + NB - 1) / NB;
    int start = blockIdx.x * slab, end = min(E, start + slab);
    for (int e = start + tid; e < end; e += 256) {
        int s, d;
        if (mult == 2) { s = ((const int2*)idx)[e].x; d = ((const int2*)idx)[(size_t)E + e].x; }
        else           { s = idx[e];                  d = idx[(size_t)E + e]; }
        unsigned pos = atomicAdd(&cur[d >> NPB_SHIFT], 1u);
        binned[pos] = ((unsigned)(d & (NPB - 1)) << 17) | (unsigned)s;
    }
}

// Fused per-bucket (1024 threads): slice-aware degree histogram -> LDS scan
// -> p0/p1 slice boundaries + dinv, then scatter binned -> col[] so each
// node's row is [slice0 srcs | slice1 srcs]. Writes land in the bucket's own
// col window -> L2-resident.
__global__ void __launch_bounds__(1024)
k_ptrfill(const unsigned* __restrict__ bucketPtr,
          const unsigned* __restrict__ binned,
          unsigned* __restrict__ p0, unsigned* __restrict__ p1,
          float* __restrict__ dinv, int* __restrict__ col,
          int n, int E, int s1) {
    __shared__ unsigned deg[NPB][2];   // 4 KB
    __shared__ unsigned cur[NPB][2];   // 4 KB
    __shared__ unsigned sh[NPB];       // 2 KB
    int tid = threadIdx.x, bb = blockIdx.x;
    for (int i = tid; i < NPB * 2; i += 1024) ((unsigned*)deg)[i] = 0;
    __syncthreads();
    unsigned start = bucketPtr[bb], end = bucketPtr[bb + 1];
    for (unsigned i = start + tid; i < end; i += 1024) {
        unsigned entry = binned[i];
        int dl = (int)(entry >> 17);
        int src = (int)(entry & 0x1FFFFu);
        atomicAdd(&deg[dl][src >= s1 ? 1 : 0], 1u);
    }
    __syncthreads();
    unsigned tot = 0, d0 = 0, d1 = 0;
    if (tid < NPB) { d0 = deg[tid][0]; d1 = deg[tid][1]; tot = d0 + d1; sh[tid] = tot; }
    __syncthreads();
    for (int off = 1; off < NPB; off <<= 1) {
        unsigned v = 0;
        if (tid < NPB && tid >= off) v = sh[tid - off];
        __syncthreads();
        if (tid < NPB) sh[tid] += v;
        __syncthreads();
    }
    if (tid < NPB) {
        unsigned base = start + sh[tid] - tot;   // exclusive prefix
        cur[tid][0] = base;
        cur[tid][1] = base + d0;
        int v = (bb << NPB_SHIFT) + tid;
        if (v < n) {
            p0[v] = base;
            p1[v] = base + d0;
            dinv[v] = rsqrtf((float)(tot + 1u));   // +1 self-loop
        }
    }
    if (bb == 0 && tid == 0) p0[n] = (unsigned)E;
    __syncthreads();
    for (unsigned i = start + tid; i < end; i += 1024) {
        unsigned entry = binned[i];
        int dl = (int)(entry >> 17);
        int src = (int)(entry & 0x1FFFFu);
        unsigned pos = atomicAdd(&cur[dl][src >= s1 ? 1 : 0], 1u);
        col[pos] = src;
    }
}

// g1[v][j] = dinv[v] * (x[v] . W1[:,j]).  16 nodes x 16 feats per block.
__global__ void k_gemm1(const float* __restrict__ x, const float* __restrict__ W1,
                        const float* __restrict__ dinv,
                        float* __restrict__ g1, int n) {
    __shared__ float w1s[F_IN * F_HID];     // 8 KB
    __shared__ float xs[16][F_IN + 4];
    int tid = threadIdx.x;
    for (int i = tid; i < F_IN * F_HID; i += 256) w1s[i] = W1[i];
    int nb = blockIdx.x * 16;
    for (int q = tid; q < 512; q += 256) {
        int r = q >> 5, k4 = q & 31;
        int g = nb + r;
        float4 v = make_float4(0.f, 0.f, 0.f, 0.f);
        if (g < n) v = ((const float4*)x)[(size_t)g * 32 + k4];
        xs[r][k4 * 4 + 0] = v.x; xs[r][k4 * 4 + 1] = v.y;
        xs[r][k4 * 4 + 2] = v.z; xs[r][k4 * 4 + 3] = v.w;
    }
    __syncthreads();
    int r = tid >> 4, j = tid & 15;
    int g = nb + r;
    if (g < n) {
        float acc = 0.f;
#pragma unroll
        for (int k = 0; k < F_IN; ++k) acc += xs[r][k] * w1s[k * F_HID + j];
        g1[(size_t)g * F_HID + j] = acc * dinv[g];
    }
}

// Pull-mode CSR aggregation over ONE src slice (full 16-wide rows, 16 lanes
// per node). Per pass all gathers hit a <=3.2 MB window of gin -> XCD-L2
// resident; col streamed NT; partial accumulator streamed NT.
// FIRST: acc = gin[v] (self-loop); else load partial from acc_io.
// LAST: epilogue (dinv, +b1/relu for layer 1) and store in place.
template <int FIRST, int LAST, int RELU>
__global__ void __launch_bounds__(256)
k_agg(const unsigned* __restrict__ pA, const unsigned* __restrict__ pB,
      const int* __restrict__ col,
      const float* __restrict__ gin, float* __restrict__ acc_io,
      const float* __restrict__ dinv, const float* __restrict__ b1, int n) {
    int t = blockIdx.x * blockDim.x + threadIdx.x;
    int v = t >> 4, j = t & 15;
    if (v >= n) return;
    size_t o = (size_t)v * F_HID + j;
    float acc;
    if (FIRST) acc = gin[o];                               // self-loop
    else       acc = __builtin_nontemporal_load(acc_io + o);
    unsigned i = pA[v], end = pB[v];
    for (; i + 8 <= end; i += 8) {
        int u0 = __builtin_nontemporal_load(col + i);
        int u1 = __builtin_nontemporal_load(col + i + 1);
        int u2 = __builtin_nontemporal_load(col + i + 2);
        int u3 = __builtin_nontemporal_load(col + i + 3);
        int u4 = __builtin_nontemporal_load(col + i + 4);
        int u5 = __builtin_nontemporal_load(col + i + 5);
        int u6 = __builtin_nontemporal_load(col + i + 6);
        int u7 = __builtin_nontemporal_load(col + i + 7);
        float a0 = gin[(size_t)u0 * F_HID + j];
        float a1 = gin[(size_t)u1 * F_HID + j];
        float a2 = gin[(size_t)u2 * F_HID + j];
        float a3 = gin[(size_t)u3 * F_HID + j];
        float a4 = gin[(size_t)u4 * F_HID + j];
        float a5 = gin[(size_t)u5 * F_HID + j];
        float a6 = gin[(size_t)u6 * F_HID + j];
        float a7 = gin[(size_t)u7 * F_HID + j];
        acc += ((a0 + a1) + (a2 + a3)) + ((a4 + a5) + (a6 + a7));
    }
    for (; i < end; ++i)
        acc += gin[(size_t)__builtin_nontemporal_load(col + i) * F_HID + j];
    if (LAST) {
        float di = dinv[v];
        float r;
        if (RELU) r = fmaxf(di * acc + b1[j], 0.f) * di;
        else      r = di * acc;
        __builtin_nontemporal_store(r, acc_io + o);
    } else {
        __builtin_nontemporal_store(acc, acc_io + o);
    }
}

// out[v][c] = B[v] . W2[:,c] + b2[c]   (dinv already folded into B)
__global__ void k_out(const float* __restrict__ B,
                      const float* __restrict__ W2, const float* __restrict__ b2,
                      float* __restrict__ out, int n) {
    __shared__ float w2s[F_HID * F_OUT];
    __shared__ float b2s[F_OUT];
    int tid = threadIdx.x;
    for (int i = tid; i < F_HID * F_OUT; i += 256) w2s[i] = W2[i];
    if (tid < F_OUT) b2s[tid] = b2[tid];
    __syncthreads();
    int total = n * F_OUT;
    int stride = gridDim.x * blockDim.x;
    for (int i = blockIdx.x * blockDim.x + tid; i < total; i += stride) {
        int node = i / F_OUT, c = i - node * F_OUT;
        float acc = 0.f;
#pragma unroll
        for (int j = 0; j < F_HID; ++j) acc += B[(size_t)node * F_HID + j] * w2s[j * F_OUT + c];
        __builtin_nontemporal_store(acc + b2s[c], out + i);
    }
}

extern "C" void kernel_launch(void* const* d_in, const int* in_sizes, int n_in,
                              void* d_out, int out_size, void* d_ws, size_t ws_size,
                              hipStream_t stream) {
    const float* x   = (const float*)d_in[0];
    const int*   idx = (const int*)d_in[1];
    const float* W1  = (const float*)d_in[2];
    const float* b1  = (const float*)d_in[3];
    const float* W2  = (const float*)d_in[4];
    const float* b2  = (const float*)d_in[5];
    float* out = (float*)d_out;

    const int n = in_sizes[0] / F_IN;       // 100000
    const int E = in_sizes[1] / 2;          // 6400000
    const int s1 = (n + 1) / 2;             // src-slice boundary (3.2 MB halves)

    char* ws = (char*)d_ws;
    size_t off = 0;
    auto carve = [&](size_t bytes) { char* p = ws + off; off += (bytes + 255) / 256 * 256; return p; };
    float*    dinv      = (float*)carve((size_t)n * 4);
    unsigned* bucketPtr = (unsigned*)carve((NBUCK + 1) * 4);
    unsigned* bucketTot = (unsigned*)carve(NBUCK * 4);
    unsigned* cnt       = (unsigned*)carve((size_t)NBUCK * NB * 4);   // 512 KB
    unsigned* p0        = (unsigned*)carve(((size_t)n + 1) * 4);
    unsigned* p1        = (unsigned*)carve((size_t)n * 4);
    float*    bufA      = (float*)carve((size_t)n * F_HID * 4);       // 6.4 MB
    float*    bufB      = (float*)carve((size_t)n * F_HID * 4);       // 6.4 MB
    // binned (E words = 25.6 MB) and col (E words) live in d_out (55.2 MB);
    // both fully consumed before k_out overwrites d_out.
    unsigned* binned = (unsigned*)d_out;
    int*      col    = (int*)d_out + (size_t)E;

    const int B = 256;
    const int nbAgg = (n * F_HID + B - 1) / B;   // 6250
    k_bincount<<<NB, B, 0, stream>>>(idx, cnt, E);
    k_scanA   <<<NBUCK, B, 0, stream>>>(cnt, bucketTot);
    k_scanB   <<<1, NBUCK, 0, stream>>>(bucketTot, bucketPtr);
    k_binfill <<<NB, B, 0, stream>>>(idx, cnt, bucketPtr, binned, E);
    k_ptrfill <<<NBUCK, 1024, 0, stream>>>(bucketPtr, binned, p0, p1, dinv, col, n, E, s1);
    k_gemm1   <<<(n + 15) / 16, B, 0, stream>>>(x, W1, dinv, bufA, n);
    // layer 1: slice-0 pass (partial), slice-1 pass (+relu epilogue)
    k_agg<1,0,0><<<nbAgg, B, 0, stream>>>(p0, p1,     col, bufA, bufB, dinv, b1, n);
    k_agg<0,1,1><<<nbAgg, B, 0, stream>>>(p1, p0 + 1, col, bufA, bufB, dinv, b1, n);
    // layer 2
    k_agg<1,0,0><<<nbAgg, B, 0, stream>>>(p0, p1,     col, bufB, bufA, dinv, b1, n);
    k_agg<0,1,0><<<nbAgg, B, 0, stream>>>(p1, p0 + 1, col, bufB, bufA, dinv, b1, n);
    k_out     <<<8192, B, 0, stream>>>(bufA, W2, b2, out, n);
}